// Round 2
// baseline (444.857 us; speedup 1.0000x reference)
//
#include <hip/hip_runtime.h>

// FullyConnectedTensorProduct, B=2^20 rows of 32 f32 each side.
//   s1=x1[0:8], v1=x1[8:32] as (8,3); same for x2.
//   out0[w]   = sum_uv s1[u]s2[v]W0[uvw] + (1/sqrt3) sum_uv (v1[u].v2[v]) W1[uvw]
//   out1[w,k] = sum_uv s1[u]v2[v,k]W2[uvw] + sum_uv v1[u,k]s2[v]W3[uvw]
// v2 change vs v1: weights (8KB, batch-uniform) staged in LDS, read as
// all-lane broadcast float4 (ds_read_b128, conflict-free) instead of s_load
// round-trips through the 112-SGPR buffer. W2 inner-sum fused into the
// W0/W1 (v,u) sweep. ~2800 FMA/row factored form.

constexpr int TPB = 256;

__global__ __launch_bounds__(TPB) void tp_kernel(
    const float* __restrict__ x1,
    const float* __restrict__ x2,
    const float* __restrict__ wg,
    float* __restrict__ out,
    int batch)
{
    const float INV3  = 0.57735026918962576f;   // 1/sqrt(3)
    const float ALPHA = 0.088388347648318447f;  // 1/sqrt(128)

    __shared__ alignas(16) float W[2048];       // W0|W1|W2|W3, 512 floats each

    int b = blockIdx.x * TPB + threadIdx.x;

    // ---- issue input loads first (overlap with weight staging) ----
    float X1[32], X2[32];
    {
        const float4* p1 = (const float4*)(x1 + (size_t)b * 32);
        const float4* p2 = (const float4*)(x2 + (size_t)b * 32);
        #pragma unroll
        for (int j = 0; j < 8; ++j) {
            float4 t1 = p1[j];
            X1[4*j+0] = t1.x; X1[4*j+1] = t1.y; X1[4*j+2] = t1.z; X1[4*j+3] = t1.w;
            float4 t2 = p2[j];
            X2[4*j+0] = t2.x; X2[4*j+1] = t2.y; X2[4*j+2] = t2.z; X2[4*j+3] = t2.w;
        }
    }

    // ---- stage weights to LDS (coalesced: 256 threads x 2 float4) ----
    {
        const float4* ws = (const float4*)wg;
        float4* wd = (float4*)W;
        int t = threadIdx.x;
        wd[t]       = ws[t];
        wd[t + 256] = ws[t + 256];
    }
    __syncthreads();

    if (b >= batch) return;

    float acc0[8], acc0b[8], acc1[8][3];
    #pragma unroll
    for (int t = 0; t < 8; ++t) {
        acc0[t] = 0.f; acc0b[t] = 0.f;
        acc1[t][0] = 0.f; acc1[t][1] = 0.f; acc1[t][2] = 0.f;
    }

    // ---- Sweep 1 (v outer, u inner): W0, W1, and W2 partial e[t] ----
    // e[t] = sum_u s1[u]*W2[u,v,t]; then acc1[t][k] += v2[v,k]*e[t]
    #pragma unroll
    for (int v = 0; v < 8; ++v) {
        float s2v = X2[v];
        float c0 = X2[8+v*3+0], c1 = X2[8+v*3+1], c2 = X2[8+v*3+2];
        float e[8];
        #pragma unroll
        for (int t = 0; t < 8; ++t) e[t] = 0.f;

        #pragma unroll
        for (int u = 0; u < 8; ++u) {
            float s1u = X1[u];
            float p = s1u * s2v;
            float d = X1[8+u*3+0]*c0 + X1[8+u*3+1]*c1 + X1[8+u*3+2]*c2;
            const float4* w0 = (const float4*)&W[u*64 + v*8];          // W0[u][v][:]
            const float4* w1 = (const float4*)&W[512 + u*64 + v*8];    // W1
            const float4* w2 = (const float4*)&W[1024 + u*64 + v*8];   // W2
            float4 a0 = w0[0], b0 = w0[1];
            float4 a1 = w1[0], b1 = w1[1];
            float4 a2 = w2[0], b2 = w2[1];
            acc0[0] += p*a0.x; acc0[1] += p*a0.y; acc0[2] += p*a0.z; acc0[3] += p*a0.w;
            acc0[4] += p*b0.x; acc0[5] += p*b0.y; acc0[6] += p*b0.z; acc0[7] += p*b0.w;
            acc0b[0] += d*a1.x; acc0b[1] += d*a1.y; acc0b[2] += d*a1.z; acc0b[3] += d*a1.w;
            acc0b[4] += d*b1.x; acc0b[5] += d*b1.y; acc0b[6] += d*b1.z; acc0b[7] += d*b1.w;
            e[0] += s1u*a2.x; e[1] += s1u*a2.y; e[2] += s1u*a2.z; e[3] += s1u*a2.w;
            e[4] += s1u*b2.x; e[5] += s1u*b2.y; e[6] += s1u*b2.z; e[7] += s1u*b2.w;
        }
        #pragma unroll
        for (int t = 0; t < 8; ++t) {
            acc1[t][0] += c0 * e[t];
            acc1[t][1] += c1 * e[t];
            acc1[t][2] += c2 * e[t];
        }
    }

    // ---- Sweep 2 (u outer, v inner): W3 ----
    // f[t] = sum_v s2[v]*W3[u,v,t]; then acc1[t][k] += v1[u,k]*f[t]
    #pragma unroll
    for (int u = 0; u < 8; ++u) {
        float f[8];
        #pragma unroll
        for (int t = 0; t < 8; ++t) f[t] = 0.f;
        #pragma unroll
        for (int v = 0; v < 8; ++v) {
            float sv = X2[v];
            const float4* w3 = (const float4*)&W[1536 + u*64 + v*8];   // W3
            float4 a3 = w3[0], b3 = w3[1];
            f[0] += sv*a3.x; f[1] += sv*a3.y; f[2] += sv*a3.z; f[3] += sv*a3.w;
            f[4] += sv*b3.x; f[5] += sv*b3.y; f[6] += sv*b3.z; f[7] += sv*b3.w;
        }
        float c0 = X1[8+u*3+0], c1 = X1[8+u*3+1], c2 = X1[8+u*3+2];
        #pragma unroll
        for (int t = 0; t < 8; ++t) {
            acc1[t][0] += c0 * f[t];
            acc1[t][1] += c1 * f[t];
            acc1[t][2] += c2 * f[t];
        }
    }

    // ---- epilogue: scale + pack + vectorized store ----
    float O[32];
    #pragma unroll
    for (int t = 0; t < 8; ++t) O[t] = ALPHA * (acc0[t] + INV3 * acc0b[t]);
    #pragma unroll
    for (int t = 0; t < 8; ++t) {
        O[8 + t*3 + 0] = ALPHA * acc1[t][0];
        O[8 + t*3 + 1] = ALPHA * acc1[t][1];
        O[8 + t*3 + 2] = ALPHA * acc1[t][2];
    }
    float4* po = (float4*)(out + (size_t)b * 32);
    #pragma unroll
    for (int j = 0; j < 8; ++j) {
        po[j] = make_float4(O[4*j+0], O[4*j+1], O[4*j+2], O[4*j+3]);
    }
}

extern "C" void kernel_launch(void* const* d_in, const int* in_sizes, int n_in,
                              void* d_out, int out_size, void* d_ws, size_t ws_size,
                              hipStream_t stream) {
    const float* x1 = (const float*)d_in[0];
    const float* x2 = (const float*)d_in[1];
    const float* wg = (const float*)d_in[2];
    float* out = (float*)d_out;

    int batch = in_sizes[0] / 32;
    dim3 grid((batch + TPB - 1) / TPB), block(TPB);
    hipLaunchKernelGGL(tp_kernel, grid, block, 0, stream, x1, x2, wg, out, batch);
}

// Round 3
// 369.534 us; speedup vs baseline: 1.2038x; 1.2038x over previous
//
#include <hip/hip_runtime.h>

// FullyConnectedTensorProduct, B=2^20 rows of 32 f32 each side.
//   s1=x1[0:8], v1=x1[8:32] as (8,3); same for x2.
//   out0[w]   = sum_uv s1[u]s2[v]W0[uvw] + (1/sqrt3) sum_uv (v1[u].v2[v]) W1[uvw]
//   out1[w,k] = sum_uv s1[u]v2[v,k]W2[uvw] + sum_uv v1[u,k]s2[v]W3[uvw]
// v3: weights via s_load (v1 path — LDS broadcast was LDS-pipe-bound in v2),
// all t-indexed FMA chains packed as <2 x float> -> v_pk_fma_f32. Halves the
// VALU instruction count and shrinks the unrolled body below the 32KB I$.

typedef float v2f __attribute__((ext_vector_type(2)));

constexpr int TPB = 256;

__global__ __launch_bounds__(TPB) void tp_kernel(
    const float* __restrict__ x1,
    const float* __restrict__ x2,
    const float* __restrict__ wg,
    float* __restrict__ out,
    int batch)
{
    const float INV3  = 0.57735026918962576f;   // 1/sqrt(3)
    const float ALPHA = 0.088388347648318447f;  // 1/sqrt(128)

    int b = blockIdx.x * TPB + threadIdx.x;
    if (b >= batch) return;

    // ---- load inputs (8 x float4 each; rows are 128B aligned) ----
    float X1[32], X2[32];
    {
        const float4* p1 = (const float4*)(x1 + (size_t)b * 32);
        const float4* p2 = (const float4*)(x2 + (size_t)b * 32);
        #pragma unroll
        for (int j = 0; j < 8; ++j) {
            float4 t1 = p1[j];
            X1[4*j+0] = t1.x; X1[4*j+1] = t1.y; X1[4*j+2] = t1.z; X1[4*j+3] = t1.w;
            float4 t2 = p2[j];
            X2[4*j+0] = t2.x; X2[4*j+1] = t2.y; X2[4*j+2] = t2.z; X2[4*j+3] = t2.w;
        }
    }

    // accumulators: acc0/acc0b pack out0 t-pairs; a01[t]=out1[t][k0,k1], a2[t]=out1[t][2]
    v2f acc0[4], acc0b[4], a01[8];
    float a2[8];
    #pragma unroll
    for (int j = 0; j < 4; ++j) { acc0[j] = (v2f){0.f,0.f}; acc0b[j] = (v2f){0.f,0.f}; }
    #pragma unroll
    for (int t = 0; t < 8; ++t) { a01[t] = (v2f){0.f,0.f}; a2[t] = 0.f; }

    // ---- Sweep 1 (v outer, u inner): W0, W1, and W2 partials ----
    #pragma unroll
    for (int v = 0; v < 8; ++v) {
        float s2v = X2[v];
        float c0 = X2[8+v*3+0], c1 = X2[8+v*3+1], c2 = X2[8+v*3+2];
        v2f cc01 = {c0, c1};
        v2f e[4] = {{0.f,0.f},{0.f,0.f},{0.f,0.f},{0.f,0.f}};

        #pragma unroll
        for (int u = 0; u < 8; ++u) {
            float s1u = X1[u];
            float p = s1u * s2v;
            float d = X1[8+u*3+0]*c0 + X1[8+u*3+1]*c1 + X1[8+u*3+2]*c2;
            v2f pp = {p, p}, dd = {d, d}, ss = {s1u, s1u};
            const v2f* w0 = (const v2f*)(wg +         u*64 + v*8);  // W0[u][v][:]
            const v2f* w1 = (const v2f*)(wg +  512 +  u*64 + v*8);  // W1
            const v2f* w2 = (const v2f*)(wg + 1024 +  u*64 + v*8);  // W2
            #pragma unroll
            for (int j = 0; j < 4; ++j) {
                acc0[j]  = __builtin_elementwise_fma(pp, w0[j], acc0[j]);
                acc0b[j] = __builtin_elementwise_fma(dd, w1[j], acc0b[j]);
                e[j]     = __builtin_elementwise_fma(ss, w2[j], e[j]);
            }
        }
        #pragma unroll
        for (int j = 0; j < 4; ++j) {
            float e0 = e[j].x, e1 = e[j].y;
            v2f ee0 = {e0, e0}, ee1 = {e1, e1};
            a01[2*j]   = __builtin_elementwise_fma(cc01, ee0, a01[2*j]);
            a01[2*j+1] = __builtin_elementwise_fma(cc01, ee1, a01[2*j+1]);
            a2[2*j]   += c2 * e0;
            a2[2*j+1] += c2 * e1;
        }
    }

    // ---- Sweep 2 (u outer, v inner): W3 ----
    #pragma unroll
    for (int u = 0; u < 8; ++u) {
        v2f f[4] = {{0.f,0.f},{0.f,0.f},{0.f,0.f},{0.f,0.f}};
        #pragma unroll
        for (int v = 0; v < 8; ++v) {
            float sv = X2[v];
            v2f ss = {sv, sv};
            const v2f* w3 = (const v2f*)(wg + 1536 + u*64 + v*8);   // W3
            #pragma unroll
            for (int j = 0; j < 4; ++j)
                f[j] = __builtin_elementwise_fma(ss, w3[j], f[j]);
        }
        float c0 = X1[8+u*3+0], c1 = X1[8+u*3+1], c2 = X1[8+u*3+2];
        v2f cc01 = {c0, c1};
        #pragma unroll
        for (int j = 0; j < 4; ++j) {
            float f0 = f[j].x, f1 = f[j].y;
            v2f ff0 = {f0, f0}, ff1 = {f1, f1};
            a01[2*j]   = __builtin_elementwise_fma(cc01, ff0, a01[2*j]);
            a01[2*j+1] = __builtin_elementwise_fma(cc01, ff1, a01[2*j+1]);
            a2[2*j]   += c2 * f0;
            a2[2*j+1] += c2 * f1;
        }
    }

    // ---- epilogue: scale + pack + vectorized store ----
    float O[32];
    #pragma unroll
    for (int j = 0; j < 4; ++j) {
        v2f iv = {INV3, INV3}, al = {ALPHA, ALPHA};
        v2f o = al * (acc0[j] + iv * acc0b[j]);
        O[2*j]   = o.x;
        O[2*j+1] = o.y;
    }
    #pragma unroll
    for (int t = 0; t < 8; ++t) {
        O[8 + t*3 + 0] = ALPHA * a01[t].x;
        O[8 + t*3 + 1] = ALPHA * a01[t].y;
        O[8 + t*3 + 2] = ALPHA * a2[t];
    }
    float4* po = (float4*)(out + (size_t)b * 32);
    #pragma unroll
    for (int j = 0; j < 8; ++j) {
        po[j] = make_float4(O[4*j+0], O[4*j+1], O[4*j+2], O[4*j+3]);
    }
}

extern "C" void kernel_launch(void* const* d_in, const int* in_sizes, int n_in,
                              void* d_out, int out_size, void* d_ws, size_t ws_size,
                              hipStream_t stream) {
    const float* x1 = (const float*)d_in[0];
    const float* x2 = (const float*)d_in[1];
    const float* wg = (const float*)d_in[2];
    float* out = (float*)d_out;

    int batch = in_sizes[0] / 32;
    dim3 grid((batch + TPB - 1) / TPB), block(TPB);
    hipLaunchKernelGGL(tp_kernel, grid, block, 0, stream, x1, x2, wg, out, batch);
}